// Round 10
// baseline (30.826 us; speedup 1.0000x reference)
//
#include <hip/hip_runtime.h>

typedef __attribute__((ext_vector_type(4))) float f32x4;
typedef __attribute__((ext_vector_type(8))) _Float16 f16x8;

#define D_ 64
#define K_ 512

// 2-limb f16: a = hi + lo (22 mantissa bits), limbs K-concatenated.
// k-blocks: kb0 = dims 0..31 hi, kb1 = dims 32..63 hi, kb2/kb3 = same dims lo.
// Within a frag, lane l (lh=l>>4, ll=l&15) holds s=0..7 -> dim d = lh*4+16*(s>>2)+(s&3)
// (+32 for the kb1/kb3 frags). IDENTICAL builder for codebook (A/M operand) and
// queries (B/N operand) => any within-K-block lane permutation cancels in A.B.
// Queries are NEGATED at conversion; acc seeded with 0.5||e||^2 via the MFMA
// C-operand: score = 0.5||e||^2 - c.e (lo.lo product dropped, ~1.5e-5 error).
//
// Structure: grid 256 x 512 thr (8 waves, 2/SIMD), Q=256/block. Wave w owns
// entries 64w..64w+63 in registers (ef). Query frags are built PER WAVE straight
// from global (L2-hot 16KB/chunk) -> NO LDS staging, NO barriers in the main
// loop; waves run free and only sync once at the end to combine argmins.
__global__ __launch_bounds__(512, 2)
void vq_fused(const float* __restrict__ codes,
              const float* __restrict__ codebook,
              float* __restrict__ out) {
  __shared__ float esq_s[K_];            // 2 KB
  __shared__ float smin[8][256];         // 8 KB
  __shared__ int   simin[8][256];        // 8 KB
  __shared__ int   best[256];            // 1 KB

  const int t = threadIdx.x;
  const int w = t >> 6, l = t & 63, lh = l >> 4, ll = l & 15;
  const long long qb = (long long)blockIdx.x * 256;

  // ---- build ef frags + 0.5||e||^2 in-register (once per block) ----
  f16x8 ef[4][4];
#pragma unroll
  for (int i = 0; i < 4; ++i) {
    const int e = (w * 4 + i) * 16 + ll;
    const float* src = codebook + e * D_ + lh * 4;
    _Float16 hi[4][4], lo[4][4];
    float es = 0.f;
#pragma unroll
    for (int j = 0; j < 4; ++j) {
      f32x4 v = *(const f32x4*)(src + 16 * j);
#pragma unroll
      for (int si = 0; si < 4; ++si) {
        float a = v[si];
        es += a * a;
        _Float16 h = (_Float16)a;
        hi[j][si] = h;
        lo[j][si] = (_Float16)(a - (float)h);
      }
    }
    es += __shfl_xor(es, 16, 64);         // sum the 4 lh groups
    es += __shfl_xor(es, 32, 64);
    if (lh == 0) esq_s[e] = 0.5f * es;
#pragma unroll
    for (int s = 0; s < 8; ++s) {
      ef[i][0][s] = hi[s >> 2][s & 3];          // dims 0..31  hi
      ef[i][1][s] = hi[2 + (s >> 2)][s & 3];    // dims 32..63 hi
      ef[i][2][s] = lo[s >> 2][s & 3];          // dims 0..31  lo
      ef[i][3][s] = lo[2 + (s >> 2)][s & 3];    // dims 32..63 lo
    }
  }
  __syncthreads();                        // esq_s visible (only block-wide sync #1)

  // per-lane 0.5||e||^2 for C/D rows: entries (w*4+i)*16 + lh*4 + r
  f32x4 esqr[4];
#pragma unroll
  for (int i = 0; i < 4; ++i)
    esqr[i] = *(const f32x4*)(esq_s + (w * 4 + i) * 16 + lh * 4);

  // ---- main loop: barrier-free; query frags straight from global (L2-hot) ----
  for (int c = 0; c < 4; ++c) {
    float mv[4]; int mi[4];
#pragma unroll
    for (int qt = 0; qt < 4; ++qt) {
      // lane reads its query row: q = qt*16+ll, dims lh*4 + {0,16,32,48}..+3
      const float* src = codes + (qb + c * 64 + qt * 16 + ll) * D_ + lh * 4;
      f32x4 v[4];
#pragma unroll
      for (int j = 0; j < 4; ++j) v[j] = *(const f32x4*)(src + 16 * j);

      // negated 2-limb conversion, same frag builder as ef
      f16x8 qh0, qh1, ql0, ql1;
#pragma unroll
      for (int s = 0; s < 8; ++s) {
        const int j = s >> 2, si = s & 3;
        float na0 = -v[j][si];
        _Float16 h0 = (_Float16)na0;
        qh0[s] = h0; ql0[s] = (_Float16)(na0 - (float)h0);
        float na1 = -v[2 + j][si];
        _Float16 h1 = (_Float16)na1;
        qh1[s] = h1; ql1[s] = (_Float16)(na1 - (float)h1);
      }

      mv[qt] = 3.4e38f; mi[qt] = 0;
#pragma unroll
      for (int i = 0; i < 4; ++i) {
        f32x4 a = esqr[i];                // C seed: 0.5||e||^2
        a = __builtin_amdgcn_mfma_f32_16x16x32_f16(ef[i][0], qh0, a, 0, 0, 0); // eh.(-ch)
        a = __builtin_amdgcn_mfma_f32_16x16x32_f16(ef[i][1], qh1, a, 0, 0, 0);
        a = __builtin_amdgcn_mfma_f32_16x16x32_f16(ef[i][2], qh0, a, 0, 0, 0); // el.(-ch)
        a = __builtin_amdgcn_mfma_f32_16x16x32_f16(ef[i][3], qh1, a, 0, 0, 0);
        a = __builtin_amdgcn_mfma_f32_16x16x32_f16(ef[i][0], ql0, a, 0, 0, 0); // eh.(-cl)
        a = __builtin_amdgcn_mfma_f32_16x16x32_f16(ef[i][1], ql1, a, 0, 0, 0);
#pragma unroll
        for (int r = 0; r < 4; ++r) {
          const int e = (w * 4 + i) * 16 + lh * 4 + r;   // ascending: first-min wins
          if (a[r] < mv[qt]) { mv[qt] = a[r]; mi[qt] = e; }
        }
      }
      // reduce over the 4 lh groups (same query col, different entries)
#pragma unroll
      for (int off = 16; off <= 32; off <<= 1) {
        float ov = __shfl_xor(mv[qt], off, 64);
        int oi = __shfl_xor(mi[qt], off, 64);
        if (ov < mv[qt] || (ov == mv[qt] && oi < mi[qt])) { mv[qt] = ov; mi[qt] = oi; }
      }
    }
    if (l < 16) {
#pragma unroll
      for (int qt = 0; qt < 4; ++qt) {
        smin[w][c * 64 + qt * 16 + ll] = mv[qt];
        simin[w][c * 64 + qt * 16 + ll] = mi[qt];
      }
    }
  }

  __syncthreads();                        // block-wide sync #2: all smin written

  // ---- combine 8 waves (disjoint ascending entry ranges; tie -> lower index) ----
  if (t < 256) {
    float bv = smin[0][t]; int bi = simin[0][t];
#pragma unroll
    for (int ww = 1; ww < 8; ++ww) {
      float v = smin[ww][t]; int ii = simin[ww][t];
      if (v < bv || (v == bv && ii < bi)) { bv = v; bi = ii; }
    }
    best[t] = bi;
  }
  __syncthreads();

  // ---- gather: exact fp32 rows from global codebook (L2-hot) ----
#pragma unroll
  for (int i2 = 0; i2 < 8; ++i2) {
    const int f = t + 512 * i2;           // 4096 f32x4 per block
    const int q = f >> 4, g = f & 15;
    const int e = best[q];
    f32x4 v = *(const f32x4*)(codebook + e * D_ + g * 4);
    *(f32x4*)(out + (qb + q) * D_ + g * 4) = v;
  }
}

extern "C" void kernel_launch(void* const* d_in, const int* in_sizes, int n_in,
                              void* d_out, int out_size, void* d_ws, size_t ws_size,
                              hipStream_t stream) {
  const float* codes = (const float*)d_in[0];
  const float* codebook = (const float*)d_in[1];
  float* out = (float*)d_out;
  const int Q = in_sizes[0] / D_;        // 65536
  const int grid = Q / 256;              // 256
  vq_fused<<<grid, 512, 0, stream>>>(codes, codebook, out);
}

// Round 11
// 26.170 us; speedup vs baseline: 1.1779x; 1.1779x over previous
//
#include <hip/hip_runtime.h>

typedef __attribute__((ext_vector_type(4))) float f32x4;
typedef __attribute__((ext_vector_type(8))) _Float16 f16x8;

#define D_ 64
#define K_ 512

// 2-limb f16: a = hi + lo (22 mantissa bits), limbs K-concatenated.
// Frag layout (identical builder for codebook and queries => within-K-block
// permutation cancels): half-off = tile*2048 + kb*512 + lh*128 + ll*8 + j*4 + si,
// where dim d (within kb's 32) = lh*4 + 16j + si. Queries NEGATED at staging;
// acc seeded with 0.5||e||^2 via MFMA C-operand: score = 0.5||e||^2 - c.e
// (lo.lo dropped, ~1.5e-5 error; absmax 0.0 across rounds 7-10).
//
// Structure: grid 256 x 512 thr (8 waves), Q=256/block, 1 block/CU.
// ALL 256 queries staged into LDS in ONE phase (64 KB) -> exactly 2 block-wide
// barriers in the whole kernel (staging, argmin-combine). Wave w owns entries
// 64w..64w+63 in registers and sweeps 16 q-tiles barrier-free.
__global__ __launch_bounds__(512, 1)
void vq_fused(const float* __restrict__ codes,
              const float* __restrict__ codebook,
              float* __restrict__ out) {
  __shared__ _Float16 Af[256 * 128];     // 64 KB query frags
  __shared__ float esq_s[K_];            // 2 KB
  __shared__ float smin[8][256];         // 8 KB
  __shared__ int   simin[8][256];        // 8 KB
  __shared__ int   best[256];            // 1 KB

  const int t = threadIdx.x;
  const int w = t >> 6, l = t & 63, lh = l >> 4, ll = l & 15;
  const long long qb = (long long)blockIdx.x * 256;

  // ---- issue all query loads first (HBM latency hides under ef build) ----
  // thread covers query aq = (w&3)*64 + l, dim half dhalf = (w>>2)*32
  const int aq = (w & 3) * 64 + l;
  const int dhalf = (w >> 2) * 32;
  const float* asrc = codes + (qb + aq) * D_ + dhalf;
  f32x4 av[8];
#pragma unroll
  for (int j = 0; j < 8; ++j) av[j] = *(const f32x4*)(asrc + 4 * j);

  // ---- build ef frags + 0.5||e||^2 in-register (once per block) ----
  f16x8 ef[4][4];
#pragma unroll
  for (int i = 0; i < 4; ++i) {
    const int e = (w * 4 + i) * 16 + ll;
    const float* src = codebook + e * D_ + lh * 4;
    _Float16 hi[4][4], lo[4][4];
    float es = 0.f;
#pragma unroll
    for (int j = 0; j < 4; ++j) {
      f32x4 v = *(const f32x4*)(src + 16 * j);
#pragma unroll
      for (int si = 0; si < 4; ++si) {
        float a = v[si];
        es += a * a;
        _Float16 h = (_Float16)a;
        hi[j][si] = h;
        lo[j][si] = (_Float16)(a - (float)h);
      }
    }
    es += __shfl_xor(es, 16, 64);         // sum the 4 lh groups
    es += __shfl_xor(es, 32, 64);
    if (lh == 0) esq_s[e] = 0.5f * es;
#pragma unroll
    for (int s = 0; s < 8; ++s) {
      ef[i][0][s] = hi[s >> 2][s & 3];          // dims 0..31  hi
      ef[i][1][s] = hi[2 + (s >> 2)][s & 3];    // dims 32..63 hi
      ef[i][2][s] = lo[s >> 2][s & 3];          // dims 0..31  lo
      ef[i][3][s] = lo[2 + (s >> 2)][s & 3];    // dims 32..63 lo
    }
  }

  // ---- stage queries: negated 2-limb frags, ds_write_b128 x8 per thread ----
  {
    const int kb = dhalf >> 5;                  // 0 or 1
    _Float16* base = Af + (aq >> 4) * 2048 + kb * 512 + (aq & 15) * 8;
#pragma unroll
    for (int pp = 0; pp < 4; ++pp) {            // lh-group pp: dims dhalf+4pp, +16
      f16x8 wh, wl;
#pragma unroll
      for (int si = 0; si < 4; ++si) {
        float a0 = -av[pp][si];                 // j=0 part (s=0..3)
        _Float16 h0 = (_Float16)a0;
        wh[si] = h0; wl[si] = (_Float16)(a0 - (float)h0);
        float a1 = -av[pp + 4][si];             // j=1 part (s=4..7)
        _Float16 h1 = (_Float16)a1;
        wh[4 + si] = h1; wl[4 + si] = (_Float16)(a1 - (float)h1);
      }
      *(f16x8*)(base + pp * 128) = wh;          // hi limb: kb
      *(f16x8*)(base + 1024 + pp * 128) = wl;   // lo limb: kb+2
    }
  }
  __syncthreads();                              // barrier #1: Af + esq_s ready

  // per-lane 0.5||e||^2 for C/D rows: entries (w*4+i)*16 + lh*4 + r
  f32x4 esqr[4];
#pragma unroll
  for (int i = 0; i < 4; ++i)
    esqr[i] = *(const f32x4*)(esq_s + (w * 4 + i) * 16 + lh * 4);

  // ---- main loop: 16 q-tiles, barrier-free ----
#pragma unroll 2
  for (int qt = 0; qt < 16; ++qt) {
    f16x8 qf[4];
#pragma unroll
    for (int kb = 0; kb < 4; ++kb)
      qf[kb] = *(const f16x8*)(&Af[qt * 2048 + kb * 512 + l * 8]);
    float mv = 3.4e38f; int mi = 0;
#pragma unroll
    for (int i = 0; i < 4; ++i) {
      f32x4 a = esqr[i];                        // C seed: 0.5||e||^2
      a = __builtin_amdgcn_mfma_f32_16x16x32_f16(ef[i][0], qf[0], a, 0, 0, 0); // eh.(-ch)
      a = __builtin_amdgcn_mfma_f32_16x16x32_f16(ef[i][1], qf[1], a, 0, 0, 0);
      a = __builtin_amdgcn_mfma_f32_16x16x32_f16(ef[i][2], qf[0], a, 0, 0, 0); // el.(-ch)
      a = __builtin_amdgcn_mfma_f32_16x16x32_f16(ef[i][3], qf[1], a, 0, 0, 0);
      a = __builtin_amdgcn_mfma_f32_16x16x32_f16(ef[i][0], qf[2], a, 0, 0, 0); // eh.(-cl)
      a = __builtin_amdgcn_mfma_f32_16x16x32_f16(ef[i][1], qf[3], a, 0, 0, 0);
#pragma unroll
      for (int r = 0; r < 4; ++r) {
        const int e = (w * 4 + i) * 16 + lh * 4 + r;   // ascending: first-min wins
        if (a[r] < mv) { mv = a[r]; mi = e; }
      }
    }
    // reduce over the 4 lh groups (same query col, different entries)
#pragma unroll
    for (int off = 16; off <= 32; off <<= 1) {
      float ov = __shfl_xor(mv, off, 64);
      int oi = __shfl_xor(mi, off, 64);
      if (ov < mv || (ov == mv && oi < mi)) { mv = ov; mi = oi; }
    }
    if (l < 16) {
      smin[w][qt * 16 + ll] = mv;
      simin[w][qt * 16 + ll] = mi;
    }
  }
  __syncthreads();                              // barrier #2: all smin written

  // ---- combine 8 waves (disjoint ascending entry ranges; tie -> lower index) ----
  if (t < 256) {
    float bv = smin[0][t]; int bi = simin[0][t];
#pragma unroll
    for (int ww = 1; ww < 8; ++ww) {
      float v = smin[ww][t]; int ii = simin[ww][t];
      if (v < bv || (v == bv && ii < bi)) { bv = v; bi = ii; }
    }
    best[t] = bi;
  }
  __syncthreads();

  // ---- gather: exact fp32 rows from global codebook (L2-hot) ----
#pragma unroll
  for (int i2 = 0; i2 < 8; ++i2) {
    const int f = t + 512 * i2;                 // 4096 f32x4 per block
    const int q = f >> 4, g = f & 15;
    const int e = best[q];
    f32x4 v = *(const f32x4*)(codebook + e * D_ + g * 4);
    *(f32x4*)(out + (qb + q) * D_ + g * 4) = v;
  }
}

extern "C" void kernel_launch(void* const* d_in, const int* in_sizes, int n_in,
                              void* d_out, int out_size, void* d_ws, size_t ws_size,
                              hipStream_t stream) {
  const float* codes = (const float*)d_in[0];
  const float* codebook = (const float*)d_in[1];
  float* out = (float*)d_out;
  const int Q = in_sizes[0] / D_;        // 65536
  const int grid = Q / 256;              // 256
  vq_fused<<<grid, 512, 0, stream>>>(codes, codebook, out);
}